// Round 1
// baseline (513.765 us; speedup 1.0000x reference)
//
#include <hip/hip_runtime.h>

#define VN 5023
#define KN 8
#define BN 64
#define CIN 3
#define CH 64
#define MN 9
#define LAT 128
#define KTOT (VN*CH)      // 321472 = V*C_HID
#define NBV (BN*VN)       // 321472 = B*V (coincidence)
#define KC 256
#define NCHUNK ((KTOT + KC - 1)/KC)   // 1256

// ---------------- kernel 1: conv1 (x[B,V,3] -> h[B,V,64], relu) --------------
__global__ __launch_bounds__(256) void k_conv1(
    const float* __restrict__ x, const float* __restrict__ aw,
    const int* __restrict__ dst,
    const float* __restrict__ u_e, const float* __restrict__ c_e,
    const float* __restrict__ W_e, const float* __restrict__ b_e,
    float* __restrict__ h)
{
  int t = blockIdx.x*256 + threadIdx.x;
  if (t >= NBV) return;
  int b = t / VN, v = t - b*VN;
  const float* xb = x + (size_t)b*VN*CIN;
  float xi0 = xb[v*3+0], xi1 = xb[v*3+1], xi2 = xb[v*3+2];
  float Ti[MN];
#pragma unroll
  for (int m=0;m<MN;m++)
    Ti[m] = xi0*u_e[m] + xi1*u_e[MN+m] + xi2*u_e[2*MN+m] + c_e[m];
  float agg[27];
#pragma unroll
  for (int i=0;i<27;i++) agg[i]=0.f;
  for (int k=0;k<KN;k++){
    int e = v*KN+k;
    int j = dst[e];
    float awe = aw[e];
    float xj0 = xb[j*3+0], xj1 = xb[j*3+1], xj2 = xb[j*3+2];
    float lg[MN];
#pragma unroll
    for (int m=0;m<MN;m++)
      lg[m] = Ti[m] - (xj0*u_e[m]+xj1*u_e[MN+m]+xj2*u_e[2*MN+m]);
    float mx = lg[0];
#pragma unroll
    for (int m=1;m<MN;m++) mx = fmaxf(mx, lg[m]);
    float ex[MN], s=0.f;
#pragma unroll
    for (int m=0;m<MN;m++){ ex[m] = __expf(lg[m]-mx); s += ex[m]; }
    float r = awe / s;
#pragma unroll
    for (int m=0;m<MN;m++){
      float a = ex[m]*r;
      agg[m*3+0] += a*xj0; agg[m*3+1] += a*xj1; agg[m*3+2] += a*xj2;
    }
  }
  float y[CH];
#pragma unroll
  for (int c=0;c<CH;c++) y[c] = b_e[c];
#pragma unroll
  for (int mc=0; mc<27; mc++){
    float a = agg[mc];
#pragma unroll
    for (int c=0;c<CH;c++) y[c] += a * W_e[mc*CH + c];
  }
  float* hr = h + (size_t)t*CH;
#pragma unroll
  for (int c=0;c<CH;c+=4){
    float4 o = make_float4(fmaxf(y[c],0.f),fmaxf(y[c+1],0.f),
                           fmaxf(y[c+2],0.f),fmaxf(y[c+3],0.f));
    *(float4*)(hr+c) = o;
  }
}

// ---------------- kernel 2: encoder split-K partials -------------------------
// partial[blk][b][l] = sum_{k in chunk} h[b][k] * W_enc[k][l]
__global__ __launch_bounds__(256) void k_enc(
    const float* __restrict__ h, const float* __restrict__ We,
    float* __restrict__ partial)
{
  __shared__ float sht[32*68];     // [k-within-tile][b], padded
  int t = threadIdx.x;
  int blk = blockIdx.x;
  int lid = t & 31;                // l-group: covers l = lid*4 .. lid*4+3
  int bid = t >> 5;                // 0..7 : b = bid*8 .. bid*8+7
  float acc[4][8];
#pragma unroll
  for (int j=0;j<4;j++)
#pragma unroll
    for (int i=0;i<8;i++) acc[j][i]=0.f;
  int kbase0 = blk*KC;
  int ldb = t >> 2;                // 0..63 (b row for staging)
  int seg = t & 3;                 // 0..3
  for (int t0=0; t0<KC/32; t0++){
    int kbase = kbase0 + t0*32;
#pragma unroll
    for (int u=0; u<2; u++){
      int kk = seg*8 + u*4;
      int kg = kbase + kk;
      float4 vv;
      if (kg < KTOT) vv = *(const float4*)(h + (size_t)ldb*KTOT + kg);
      else vv = make_float4(0.f,0.f,0.f,0.f);
      sht[(kk+0)*68+ldb]=vv.x; sht[(kk+1)*68+ldb]=vv.y;
      sht[(kk+2)*68+ldb]=vv.z; sht[(kk+3)*68+ldb]=vv.w;
    }
    __syncthreads();
#pragma unroll 4
    for (int kk=0; kk<32; kk++){
      int kg = kbase + kk;
      float4 w;
      if (kg < KTOT) w = *(const float4*)(We + (size_t)kg*LAT + lid*4);
      else w = make_float4(0.f,0.f,0.f,0.f);
      float4 z0 = *(const float4*)(&sht[kk*68 + bid*8]);
      float4 z1 = *(const float4*)(&sht[kk*68 + bid*8 + 4]);
      float zb[8] = {z0.x,z0.y,z0.z,z0.w,z1.x,z1.y,z1.z,z1.w};
#pragma unroll
      for (int i=0;i<8;i++){
        acc[0][i] += w.x*zb[i]; acc[1][i] += w.y*zb[i];
        acc[2][i] += w.z*zb[i]; acc[3][i] += w.w*zb[i];
      }
    }
    __syncthreads();
  }
  float* pp = partial + (size_t)blk*(BN*LAT);
#pragma unroll
  for (int i=0;i<8;i++){
    float4 o = make_float4(acc[0][i],acc[1][i],acc[2][i],acc[3][i]);
    *(float4*)(pp + (bid*8+i)*LAT + lid*4) = o;
  }
}

// ---------------- kernel 3: reduce partials -> zT[l][b] ----------------------
__global__ __launch_bounds__(256) void k_reduce(
    const float* __restrict__ partial, const float* __restrict__ b_enc,
    float* __restrict__ zT)
{
  int tg = blockIdx.x*256 + threadIdx.x;   // 0..65535
  int idx = tg >> 3;                       // 0..8191 : b*128+l
  int q = tg & 7;
  float s = 0.f;
  for (int p=q; p<NCHUNK; p+=8) s += partial[(size_t)p*(BN*LAT) + idx];
  s += __shfl_xor(s,1); s += __shfl_xor(s,2); s += __shfl_xor(s,4);
  if (q==0){
    int b = idx >> 7, l = idx & 127;
    zT[l*BN + b] = s + b_enc[l];
  }
}

// ---------------- kernel 4: decoder  d[b][vc] = z[b]·W_dec[:,vc] + b_dec -----
__global__ __launch_bounds__(256) void k_dec(
    const float* __restrict__ zT, const float* __restrict__ Wd,
    const float* __restrict__ b_dec, float* __restrict__ d)
{
  int vc = blockIdx.x*256 + threadIdx.x;
  if (vc >= KTOT) return;
  float acc[BN];
#pragma unroll
  for (int b=0;b<BN;b++) acc[b]=0.f;
  for (int l=0;l<LAT;l++){
    float w = Wd[(size_t)l*KTOT + vc];
    const float* zr = zT + l*BN;     // uniform address -> scalar loads
#pragma unroll
    for (int b=0;b<BN;b++) acc[b] += zr[b]*w;
  }
  float bd = b_dec[vc];
#pragma unroll
  for (int b=0;b<BN;b++) d[(size_t)b*KTOT + vc] = acc[b] + bd;
}

// ---------------- kernel 5: per-vertex T[9] and G[27] precompute -------------
// T[m] = d_row · u_d[:,m] ; G[m,o] = d_row · W_d[m,:,o]
__global__ __launch_bounds__(256) void k_tg(
    const float* __restrict__ d, const float* __restrict__ u_d,
    const float* __restrict__ W_d, float* __restrict__ TG)
{
  int t = blockIdx.x*256 + threadIdx.x;
  if (t >= NBV) return;
  const float* drow = d + (size_t)t*CH;
  float T[MN], G[27];
#pragma unroll
  for (int m=0;m<MN;m++) T[m]=0.f;
#pragma unroll
  for (int i=0;i<27;i++) G[i]=0.f;
#pragma unroll 4
  for (int c=0;c<CH;c++){
    float dv = drow[c];
#pragma unroll
    for (int m=0;m<MN;m++) T[m] += dv*u_d[c*MN+m];
#pragma unroll
    for (int m=0;m<MN;m++){
      G[m*3+0] += dv*W_d[(m*CH+c)*3+0];
      G[m*3+1] += dv*W_d[(m*CH+c)*3+1];
      G[m*3+2] += dv*W_d[(m*CH+c)*3+2];
    }
  }
  float* tg = TG + (size_t)t*36;
  float rr[36] = {T[0],T[1],T[2],T[3],T[4],T[5],T[6],T[7],T[8],
                  G[0],G[1],G[2],G[3],G[4],G[5],G[6],G[7],G[8],
                  G[9],G[10],G[11],G[12],G[13],G[14],G[15],G[16],G[17],
                  G[18],G[19],G[20],G[21],G[22],G[23],G[24],G[25],G[26]};
#pragma unroll
  for (int i=0;i<36;i+=4)
    *(float4*)(tg+i) = make_float4(rr[i],rr[i+1],rr[i+2],rr[i+3]);
}

// ---------------- kernel 6: attention + output -------------------------------
__global__ __launch_bounds__(256) void k_att(
    const float* __restrict__ TG, const float* __restrict__ aw,
    const int* __restrict__ dst, const float* __restrict__ c_d,
    const float* __restrict__ b_d, float* __restrict__ out)
{
  int t = blockIdx.x*256 + threadIdx.x;
  if (t >= NBV) return;
  int b = t / VN, v = t - b*VN;
  const float* TGb = TG + (size_t)b*VN*36;
  float Ti[MN];
#pragma unroll
  for (int m=0;m<MN;m++) Ti[m] = TGb[(size_t)v*36+m] + c_d[m];
  float y0=0.f, y1=0.f, y2=0.f;
  for (int k=0;k<KN;k++){
    int e = v*KN+k;
    int j = dst[e];
    float awe = aw[e];
    const float* Rp = TGb + (size_t)j*36;
    float4 q0=*(const float4*)(Rp+ 0), q1=*(const float4*)(Rp+ 4),
           q2=*(const float4*)(Rp+ 8), q3=*(const float4*)(Rp+12),
           q4=*(const float4*)(Rp+16), q5=*(const float4*)(Rp+20),
           q6=*(const float4*)(Rp+24), q7=*(const float4*)(Rp+28),
           q8=*(const float4*)(Rp+32);
    float rr[36] = {q0.x,q0.y,q0.z,q0.w, q1.x,q1.y,q1.z,q1.w,
                    q2.x,q2.y,q2.z,q2.w, q3.x,q3.y,q3.z,q3.w,
                    q4.x,q4.y,q4.z,q4.w, q5.x,q5.y,q5.z,q5.w,
                    q6.x,q6.y,q6.z,q6.w, q7.x,q7.y,q7.z,q7.w,
                    q8.x,q8.y,q8.z,q8.w};
    float lg[MN];
#pragma unroll
    for (int m=0;m<MN;m++) lg[m] = Ti[m] - rr[m];
    float mx = lg[0];
#pragma unroll
    for (int m=1;m<MN;m++) mx = fmaxf(mx, lg[m]);
    float ex[MN], s=0.f;
#pragma unroll
    for (int m=0;m<MN;m++){ ex[m] = __expf(lg[m]-mx); s += ex[m]; }
    float sc = awe / s;
#pragma unroll
    for (int m=0;m<MN;m++){
      float a = ex[m]*sc;
      y0 += a*rr[9+m*3+0]; y1 += a*rr[9+m*3+1]; y2 += a*rr[9+m*3+2];
    }
  }
  float* o = out + (size_t)t*3;
  o[0]=fmaxf(y0+b_d[0],0.f); o[1]=fmaxf(y1+b_d[1],0.f); o[2]=fmaxf(y2+b_d[2],0.f);
}

extern "C" void kernel_launch(void* const* d_in, const int* in_sizes, int n_in,
                              void* d_out, int out_size, void* d_ws, size_t ws_size,
                              hipStream_t stream) {
  const float* x     = (const float*)d_in[0];
  const float* aw    = (const float*)d_in[1];
  const float* u_e   = (const float*)d_in[2];
  const float* c_e   = (const float*)d_in[3];
  const float* W_e   = (const float*)d_in[4];
  const float* b_e   = (const float*)d_in[5];
  const float* W_enc = (const float*)d_in[6];
  const float* b_enc = (const float*)d_in[7];
  const float* W_dec = (const float*)d_in[8];
  const float* b_dec = (const float*)d_in[9];
  const float* u_d   = (const float*)d_in[10];
  const float* c_d   = (const float*)d_in[11];
  const float* W_d   = (const float*)d_in[12];
  const float* b_d   = (const float*)d_in[13];
  const int*   dst   = (const int*)d_in[15];
  float* out = (float*)d_out;

  char* ws = (char*)d_ws;
  float* hbuf = (float*)ws;                               // 82.3 MB, h then d
  size_t off1 = (size_t)NBV*CH*sizeof(float);
  float* partial = (float*)(ws + off1);                   // 41.2 MB (dead after reduce)
  float* TGbuf   = (float*)(ws + off1);                   // 46.3 MB (overlaps partial)
  size_t off2 = off1 + (size_t)NBV*36*sizeof(float);
  float* zT = (float*)(ws + off2);                        // 32 KB

  int grid_bv = (NBV + 255)/256;   // 1256

  k_conv1<<<grid_bv,256,0,stream>>>(x, aw, dst, u_e, c_e, W_e, b_e, hbuf);
  k_enc<<<NCHUNK,256,0,stream>>>(hbuf, W_enc, partial);
  k_reduce<<<256,256,0,stream>>>(partial, b_enc, zT);
  k_dec<<<grid_bv,256,0,stream>>>(zT, W_dec, b_dec, hbuf);   // d overwrites h
  k_tg<<<grid_bv,256,0,stream>>>(hbuf, u_d, W_d, TGbuf);
  k_att<<<grid_bv,256,0,stream>>>(TGbuf, aw, dst, c_d, b_d, out);
}

// Round 2
// 476.694 us; speedup vs baseline: 1.0778x; 1.0778x over previous
//
#include <hip/hip_runtime.h>

#define VN 5023
#define KN 8
#define BN 64
#define CIN 3
#define CH 64
#define MN 9
#define LAT 128
#define KTOT (VN*CH)      // 321472
#define NBV (BN*VN)       // 321472
#define KC 256
#define NCHUNK 1256       // ceil(KTOT/KC); last chunk has 192 = 6*32 valid k
#define RED_G 8
#define RED_J 157         // 1256 = 8*157 exactly

// ---------------- kernel 1: conv1 (x[B,V,3] -> h[B,V,64], relu) --------------
__global__ __launch_bounds__(256, 4) void k_conv1(
    const float* __restrict__ x, const float* __restrict__ aw,
    const int* __restrict__ dst,
    const float* __restrict__ u_e, const float* __restrict__ c_e,
    const float* __restrict__ W_e, const float* __restrict__ b_e,
    float* __restrict__ h)
{
  int t = blockIdx.x*256 + threadIdx.x;
  if (t >= NBV) return;
  int b = t / VN, v = t - b*VN;
  const float* xb = x + (size_t)b*VN*CIN;
  float xi0 = xb[v*3+0], xi1 = xb[v*3+1], xi2 = xb[v*3+2];
  float Ti[MN];
#pragma unroll
  for (int m=0;m<MN;m++)
    Ti[m] = xi0*u_e[m] + xi1*u_e[MN+m] + xi2*u_e[2*MN+m] + c_e[m];
  float agg[27];
#pragma unroll
  for (int i=0;i<27;i++) agg[i]=0.f;
  for (int k=0;k<KN;k++){
    int e = v*KN+k;
    int j = dst[e];
    float awe = aw[e];
    float xj0 = xb[j*3+0], xj1 = xb[j*3+1], xj2 = xb[j*3+2];
    float lg[MN];
#pragma unroll
    for (int m=0;m<MN;m++)
      lg[m] = Ti[m] - (xj0*u_e[m]+xj1*u_e[MN+m]+xj2*u_e[2*MN+m]);
    float mx = lg[0];
#pragma unroll
    for (int m=1;m<MN;m++) mx = fmaxf(mx, lg[m]);
    float ex[MN], s=0.f;
#pragma unroll
    for (int m=0;m<MN;m++){ ex[m] = __expf(lg[m]-mx); s += ex[m]; }
    float r = awe / s;
#pragma unroll
    for (int m=0;m<MN;m++){
      float a = ex[m]*r;
      agg[m*3+0] += a*xj0; agg[m*3+1] += a*xj1; agg[m*3+2] += a*xj2;
    }
  }
  float* hr = h + (size_t)t*CH;
  // chunked output transform: only 16 accumulators live at a time (no spill)
  for (int cc=0; cc<4; cc++){
    float y[16];
#pragma unroll
    for (int c=0;c<16;c++) y[c] = b_e[cc*16+c];
#pragma unroll
    for (int mc=0; mc<27; mc++){
      float a = agg[mc];
#pragma unroll
      for (int c=0;c<16;c++) y[c] += a * W_e[mc*CH + cc*16 + c];
    }
#pragma unroll
    for (int c=0;c<16;c+=4){
      float4 o = make_float4(fmaxf(y[c],0.f),fmaxf(y[c+1],0.f),
                             fmaxf(y[c+2],0.f),fmaxf(y[c+3],0.f));
      *(float4*)(hr + cc*16 + c) = o;
    }
  }
}

// ---------------- kernel 2: encoder split-K partials -------------------------
// partial[blk][b][l] = sum_{k in chunk} h[b][k] * W_enc[k][l]
// 128 threads: thread (lq=t&15, bq=t>>4) owns 8 l x 8 b -> 64 acc, 91% FMA mix
__global__ __launch_bounds__(128, 4) void k_enc(
    const float* __restrict__ h, const float* __restrict__ We,
    float* __restrict__ partial)
{
  __shared__ float sht[32][68];     // [k-within-32][b]
  int t = threadIdx.x;
  int blk = blockIdx.x;
  int lq = t & 15;                  // l = lq*8 .. +8
  int bq = t >> 4;                  // b = bq*8 .. +8
  float acc[8][8];
#pragma unroll
  for (int i=0;i<8;i++)
#pragma unroll
    for (int j=0;j<8;j++) acc[i][j]=0.f;
  int kbase0 = blk*KC;
  int ldb = t & 63, seg = t >> 6;   // staging: row ldb, k-half seg
  int nt0 = (blk == NCHUNK-1) ? 6 : 8;   // last chunk: 192 valid k, uniform
  for (int t0=0; t0<nt0; t0++){
    int kbase = kbase0 + t0*32;
    __syncthreads();
#pragma unroll
    for (int u=0; u<4; u++){
      int kk = seg*16 + u*4;
      float4 vv = *(const float4*)(h + (size_t)ldb*KTOT + kbase + kk);
      sht[kk+0][ldb]=vv.x; sht[kk+1][ldb]=vv.y;
      sht[kk+2][ldb]=vv.z; sht[kk+3][ldb]=vv.w;
    }
    __syncthreads();
#pragma unroll 8
    for (int kk=0; kk<32; kk++){
      const float* wr = We + (size_t)(kbase+kk)*LAT + lq*8;
      float4 w0 = *(const float4*)wr;
      float4 w1 = *(const float4*)(wr+4);
      float4 z0 = *(const float4*)(&sht[kk][bq*8]);
      float4 z1 = *(const float4*)(&sht[kk][bq*8+4]);
      float wv[8] = {w0.x,w0.y,w0.z,w0.w,w1.x,w1.y,w1.z,w1.w};
      float zv[8] = {z0.x,z0.y,z0.z,z0.w,z1.x,z1.y,z1.z,z1.w};
#pragma unroll
      for (int li=0;li<8;li++)
#pragma unroll
        for (int bi=0;bi<8;bi++) acc[li][bi] += wv[li]*zv[bi];
    }
  }
  float* pp = partial + (size_t)blk*(BN*LAT);
#pragma unroll
  for (int bi=0;bi<8;bi++){
    float4 o0 = make_float4(acc[0][bi],acc[1][bi],acc[2][bi],acc[3][bi]);
    float4 o1 = make_float4(acc[4][bi],acc[5][bi],acc[6][bi],acc[7][bi]);
    *(float4*)(pp + (bq*8+bi)*LAT + lq*8)   = o0;
    *(float4*)(pp + (bq*8+bi)*LAT + lq*8+4) = o1;
  }
}

// ---------------- kernel 3a: coalesced partial reduce: 1256 -> 8 -------------
__global__ __launch_bounds__(256) void k_red1(
    const float* __restrict__ partial, float* __restrict__ partial2)
{
  int idx = blockIdx.x*256 + threadIdx.x;   // 0..8191
  int g = blockIdx.y;                        // 0..7
  float s = 0.f;
  for (int j=0;j<RED_J;j++)
    s += partial[(size_t)(g + RED_G*j)*(BN*LAT) + idx];
  partial2[(size_t)g*(BN*LAT) + idx] = s;
}

// ---------------- kernel 3b: 8 -> zT[l][b] + bias ----------------------------
__global__ __launch_bounds__(256) void k_red2(
    const float* __restrict__ partial2, const float* __restrict__ b_enc,
    float* __restrict__ zT)
{
  int idx = blockIdx.x*256 + threadIdx.x;   // 0..8191 : b*128+l
  float s = 0.f;
#pragma unroll
  for (int g=0; g<RED_G; g++) s += partial2[(size_t)g*(BN*LAT) + idx];
  int b = idx >> 7, l = idx & 127;
  zT[l*BN + b] = s + b_enc[l];
}

// ---------------- kernel 4: decoder  d[b][vc] = z[b]·W_dec[:,vc] + b_dec -----
__global__ __launch_bounds__(256, 4) void k_dec(
    const float* __restrict__ zT, const float* __restrict__ Wd,
    const float* __restrict__ b_dec, float* __restrict__ d)
{
  int vc = blockIdx.x*256 + threadIdx.x;
  if (vc >= KTOT) return;
  float acc[BN];
#pragma unroll
  for (int b=0;b<BN;b++) acc[b]=0.f;
  for (int l=0;l<LAT;l++){
    float w = Wd[(size_t)l*KTOT + vc];
    const float* zr = zT + l*BN;     // wave-uniform -> scalar loads
#pragma unroll
    for (int bb=0;bb<16;bb++){
      float4 z = *(const float4*)(zr + bb*4);
      acc[bb*4+0] += z.x*w; acc[bb*4+1] += z.y*w;
      acc[bb*4+2] += z.z*w; acc[bb*4+3] += z.w*w;
    }
  }
  float bd = b_dec[vc];
#pragma unroll
  for (int b=0;b<BN;b++) d[(size_t)b*KTOT + vc] = acc[b] + bd;
}

// ---------------- kernel 5: per-vertex T[9] and G[27] precompute -------------
__global__ __launch_bounds__(256, 4) void k_tg(
    const float* __restrict__ d, const float* __restrict__ u_d,
    const float* __restrict__ W_d, float* __restrict__ TG)
{
  int t = blockIdx.x*256 + threadIdx.x;
  if (t >= NBV) return;
  const float* drow = d + (size_t)t*CH;
  float T[MN], G[27];
#pragma unroll
  for (int m=0;m<MN;m++) T[m]=0.f;
#pragma unroll
  for (int i=0;i<27;i++) G[i]=0.f;
  for (int c0=0;c0<CH;c0+=4){
    float4 dv = *(const float4*)(drow+c0);
    float dvv[4] = {dv.x,dv.y,dv.z,dv.w};
#pragma unroll
    for (int j=0;j<4;j++){
      int c = c0+j;
      float xv = dvv[j];
#pragma unroll
      for (int m=0;m<MN;m++) T[m] += xv*u_d[c*MN+m];
#pragma unroll
      for (int m=0;m<MN;m++){
        G[m*3+0] += xv*W_d[(m*CH+c)*3+0];
        G[m*3+1] += xv*W_d[(m*CH+c)*3+1];
        G[m*3+2] += xv*W_d[(m*CH+c)*3+2];
      }
    }
  }
  float* tg = TG + (size_t)t*36;
  float rr[36] = {T[0],T[1],T[2],T[3],T[4],T[5],T[6],T[7],T[8],
                  G[0],G[1],G[2],G[3],G[4],G[5],G[6],G[7],G[8],
                  G[9],G[10],G[11],G[12],G[13],G[14],G[15],G[16],G[17],
                  G[18],G[19],G[20],G[21],G[22],G[23],G[24],G[25],G[26]};
#pragma unroll
  for (int i=0;i<36;i+=4)
    *(float4*)(tg+i) = make_float4(rr[i],rr[i+1],rr[i+2],rr[i+3]);
}

// ---------------- kernel 6: attention + output -------------------------------
__global__ __launch_bounds__(256, 4) void k_att(
    const float* __restrict__ TG, const float* __restrict__ aw,
    const int* __restrict__ dst, const float* __restrict__ c_d,
    const float* __restrict__ b_d, float* __restrict__ out)
{
  int t = blockIdx.x*256 + threadIdx.x;
  if (t >= NBV) return;
  int b = t / VN, v = t - b*VN;
  const float* TGb = TG + (size_t)b*VN*36;
  float Ti[MN];
#pragma unroll
  for (int m=0;m<MN;m++) Ti[m] = TGb[(size_t)v*36+m] + c_d[m];
  float y0=0.f, y1=0.f, y2=0.f;
  for (int k=0;k<KN;k++){
    int e = v*KN+k;
    int j = dst[e];
    float awe = aw[e];
    const float* Rp = TGb + (size_t)j*36;
    float4 q0=*(const float4*)(Rp+ 0), q1=*(const float4*)(Rp+ 4),
           q2=*(const float4*)(Rp+ 8), q3=*(const float4*)(Rp+12),
           q4=*(const float4*)(Rp+16), q5=*(const float4*)(Rp+20),
           q6=*(const float4*)(Rp+24), q7=*(const float4*)(Rp+28),
           q8=*(const float4*)(Rp+32);
    float rr[36] = {q0.x,q0.y,q0.z,q0.w, q1.x,q1.y,q1.z,q1.w,
                    q2.x,q2.y,q2.z,q2.w, q3.x,q3.y,q3.z,q3.w,
                    q4.x,q4.y,q4.z,q4.w, q5.x,q5.y,q5.z,q5.w,
                    q6.x,q6.y,q6.z,q6.w, q7.x,q7.y,q7.z,q7.w,
                    q8.x,q8.y,q8.z,q8.w};
    float lg[MN];
#pragma unroll
    for (int m=0;m<MN;m++) lg[m] = Ti[m] - rr[m];
    float mx = lg[0];
#pragma unroll
    for (int m=1;m<MN;m++) mx = fmaxf(mx, lg[m]);
    float ex[MN], s=0.f;
#pragma unroll
    for (int m=0;m<MN;m++){ ex[m] = __expf(lg[m]-mx); s += ex[m]; }
    float sc = awe / s;
#pragma unroll
    for (int m=0;m<MN;m++){
      float a = ex[m]*sc;
      y0 += a*rr[9+m*3+0]; y1 += a*rr[9+m*3+1]; y2 += a*rr[9+m*3+2];
    }
  }
  float* o = out + (size_t)t*3;
  o[0]=fmaxf(y0+b_d[0],0.f); o[1]=fmaxf(y1+b_d[1],0.f); o[2]=fmaxf(y2+b_d[2],0.f);
}

extern "C" void kernel_launch(void* const* d_in, const int* in_sizes, int n_in,
                              void* d_out, int out_size, void* d_ws, size_t ws_size,
                              hipStream_t stream) {
  const float* x     = (const float*)d_in[0];
  const float* aw    = (const float*)d_in[1];
  const float* u_e   = (const float*)d_in[2];
  const float* c_e   = (const float*)d_in[3];
  const float* W_e   = (const float*)d_in[4];
  const float* b_e   = (const float*)d_in[5];
  const float* W_enc = (const float*)d_in[6];
  const float* b_enc = (const float*)d_in[7];
  const float* W_dec = (const float*)d_in[8];
  const float* b_dec = (const float*)d_in[9];
  const float* u_d   = (const float*)d_in[10];
  const float* c_d   = (const float*)d_in[11];
  const float* W_d   = (const float*)d_in[12];
  const float* b_d   = (const float*)d_in[13];
  const int*   dst   = (const int*)d_in[15];
  float* out = (float*)d_out;

  char* ws = (char*)d_ws;
  float* hbuf = (float*)ws;                               // 82.3 MB (h, then d)
  size_t off1 = (size_t)NBV*CH*sizeof(float);
  float* partial = (float*)(ws + off1);                   // 41.2 MB
  float* TGbuf   = (float*)(ws + off1);                   // 46.3 MB (overlaps partial)
  size_t offz = off1 + (size_t)NCHUNK*(BN*LAT)*sizeof(float);  // after partial, inside TG zone
  float* zT       = (float*)(ws + offz);                  // 32 KB
  float* partial2 = (float*)(ws + offz + (size_t)(BN*LAT)*sizeof(float)); // 256 KB
  // timeline: partial dead after red1; partial2 dead after red2; zT dead after dec;
  // TG (written by k_tg, after dec) may overwrite all of them. Total ws = off1+46.3MB.

  int grid_bv = (NBV + 255)/256;   // 1256

  k_conv1<<<grid_bv,256,0,stream>>>(x, aw, dst, u_e, c_e, W_e, b_e, hbuf);
  k_enc<<<NCHUNK,128,0,stream>>>(hbuf, W_enc, partial);
  dim3 gr1(32, RED_G);
  k_red1<<<gr1,256,0,stream>>>(partial, partial2);
  k_red2<<<32,256,0,stream>>>(partial2, b_enc, zT);
  k_dec<<<grid_bv,256,0,stream>>>(zT, W_dec, b_dec, hbuf);   // d overwrites h
  k_tg<<<grid_bv,256,0,stream>>>(hbuf, u_d, W_d, TGbuf);
  k_att<<<grid_bv,256,0,stream>>>(TGbuf, aw, dst, c_d, b_d, out);
}